// Round 10
// baseline (39.246 us; speedup 1.0000x reference)
//
#include <hip/hip_runtime.h>
#include <hip/hip_bf16.h>

typedef float f32x16 __attribute__((ext_vector_type(16)));
typedef float f32x4v __attribute__((ext_vector_type(4)));

#define GLOBAL_AS(p) ((const __attribute__((address_space(1))) void*)(p))
#define LDS_AS(p)    ((__attribute__((address_space(3))) void*)(p))

#define LP 8192
#define D 128
#define TWOEPS 2e-6f
#define CEPS 1.28e-10f   /* 128 * EPS^2 */
#define MARGIN 0.2f
#define NTILE 4160       /* 128x64 tiles: sum_{I=0}^{63} (2I+2) */
#define NBLK 1024        /* 4 blocks/CU x 256 CUs; blocks 0-63 take 5 tiles, rest 4 */
#define INV_DENOM 1.4903545e-8f  /* 1 / (8192*8191) */
#define BTILE 8192       /* B tile bytes (64 rows x 128 B) */

// ---------------- Phase A: normalize p rows -> fp8, write q8[] and w[] -------------
// 4 lanes per row, 16 rows per wave. Block 0 zeroes out[0].
__global__ __launch_bounds__(64) void rows_kernel(const float* __restrict__ p,
                                                  const float* __restrict__ n,
                                                  char* __restrict__ pb,
                                                  float* __restrict__ qarr,
                                                  float* __restrict__ warr,
                                                  float* __restrict__ out) {
    const int lane = threadIdx.x;
    if (blockIdx.x == 0 && lane == 0) out[0] = 0.0f;
    const int sub = lane & 3;    // quarter of the row (32 floats)
    const int r = lane >> 2;     // 0..15
    const int row = blockIdx.x * 16 + r;

    const float4* px = (const float4*)(p + (size_t)row * D + sub * 32);
    const float4* nx = (const float4*)(n + sub * 32);  // n row 0 (t=0)
    float4 x[8], y[8];
#pragma unroll
    for (int k = 0; k < 8; ++k) { x[k] = px[k]; y[k] = nx[k]; }

    float ssp = 0.0f, ssn = 0.0f;
#pragma unroll
    for (int k = 0; k < 8; ++k) {
        ssp += fmaf(x[k].x, x[k].x, fmaf(x[k].y, x[k].y,
               fmaf(x[k].z, x[k].z, x[k].w * x[k].w)));
        ssn += fmaf(y[k].x, y[k].x, fmaf(y[k].y, y[k].y,
               fmaf(y[k].z, y[k].z, y[k].w * y[k].w)));
    }
    ssp += __shfl_xor(ssp, 1); ssp += __shfl_xor(ssp, 2);
    ssn += __shfl_xor(ssn, 1); ssn += __shfl_xor(ssn, 2);

    const float invp = 1.0f / fmaxf(sqrtf(ssp), 1e-12f);
    const float invn = 1.0f / fmaxf(sqrtf(ssn), 1e-12f);

    float s = 0.0f, q = 0.0f, dn = 0.0f, sn = 0.0f, qn = 0.0f, q8 = 0.0f;
    int pk8[8];
#pragma unroll
    for (int k = 0; k < 8; ++k) {
        float a0 = x[k].x * invp, a1 = x[k].y * invp,
              a2 = x[k].z * invp, a3 = x[k].w * invp;
        float h0 = y[k].x * invn, h1 = y[k].y * invn,
              h2 = y[k].z * invn, h3 = y[k].w * invn;
        s  += (a0 + a1) + (a2 + a3);
        q  += fmaf(a0, a0, fmaf(a1, a1, fmaf(a2, a2, a3 * a3)));
        dn += fmaf(a0, h0, fmaf(a1, h1, fmaf(a2, h2, a3 * h3)));
        sn += (h0 + h1) + (h2 + h3);
        qn += fmaf(h0, h0, fmaf(h1, h1, fmaf(h2, h2, h3 * h3)));
        int wlo = __builtin_amdgcn_cvt_pk_fp8_f32(a0, a1, 0, false);
        int wfl = __builtin_amdgcn_cvt_pk_fp8_f32(a2, a3, wlo, true);
        pk8[k] = wfl;
        float b0 = __builtin_amdgcn_cvt_f32_fp8(wfl, 0);
        float b1 = __builtin_amdgcn_cvt_f32_fp8(wfl, 1);
        float b2 = __builtin_amdgcn_cvt_f32_fp8(wfl, 2);
        float b3 = __builtin_amdgcn_cvt_f32_fp8(wfl, 3);
        q8 += fmaf(b0, b0, fmaf(b1, b1, fmaf(b2, b2, b3 * b3)));
    }
    char* dst = pb + (size_t)row * 128 + sub * 32;
    ((int4*)dst)[0] = make_int4(pk8[0], pk8[1], pk8[2], pk8[3]);
    ((int4*)dst)[1] = make_int4(pk8[4], pk8[5], pk8[6], pk8[7]);

#pragma unroll
    for (int m = 1; m < 4; m <<= 1) {
        s += __shfl_xor(s, m);
        q += __shfl_xor(q, m);
        dn += __shfl_xor(dn, m);
        sn += __shfl_xor(sn, m);
        qn += __shfl_xor(qn, m);
        q8 += __shfl_xor(q8, m);
    }
    if (sub == 0) {
        float sq = q + qn - 2.0f * dn + TWOEPS * (s - sn) + CEPS;
        float dpn = sqrtf(fmaxf(sq, 0.0f));
        qarr[row] = q8;
        warr[row] = MARGIN - dpn;
    }
}

// ---------------- Phase B: 128x64-tile pair kernel, A-in-regs, 1 barrier/tile -------
// Tile g: I = row-group (128 rows), J = col-group (64 cols), J <= 2I+1.
//   g0(I) = I*(I+1), so I = floor((sqrt(4g+1)-1)/2) (+fixups), J = g - I*(I+1).
// J>>1 == I  -> "diag-type": single term per cell (covers the diagonal block).
// Otherwise: both ordered terms per dot.
// A fragments live in registers (reloaded on I-change, rare). B triple-buffered
// in LDS (8 KB/buffer, XOR chunk-swizzle), staged 2 tiles ahead by
// global_load_lds; ONE s_barrier per tile:
//   [vmcnt(1); barrier; A/j refresh; stage(t+2); ds_read+MFMA+epilogue]
// Safe: stage(t+2) overwrites the buffer whose readers (t-1) passed the barrier.
__global__ __launch_bounds__(512, 8) void pair_kernel(const char* __restrict__ pb,
                                                      const float* __restrict__ qarr,
                                                      const float* __restrict__ warr,
                                                      float* __restrict__ out) {
    __shared__ __align__(16) char smem[3 * BTILE + 64];
    const int tid = threadIdx.x;
    const int wave = tid >> 6, lane = tid & 63;
    const int wavei = wave >> 1, wavej = wave & 1;  // 4x2 wave grid, 32x32 out each
    const int ln31 = lane & 31;
    const int h = lane >> 5;
    const int blk = blockIdx.x;

    const int g0 = (blk < 64) ? 5 * blk : 320 + 4 * (blk - 64);
    const int nt = (blk < 64) ? 5 : 4;

    auto decode = [](int g, int& I, int& J) {
        int t = (int)((__builtin_amdgcn_sqrtf(4.0f * (float)g + 1.0f) - 1.0f) * 0.5f);
        while ((t + 1) * (t + 2) <= g) ++t;
        while (t * (t + 1) > g) --t;
        I = t;
        J = g - t * (t + 1);
    };

    // stage B tile of g into LDS slot (1 global_load_lds x16B per wave)
    auto stage = [&](int g, int slot) {
        int I, J;
        decode(g, I, J);
        const char* gB = pb + (size_t)J * BTILE;  // rows J*64..+64, row-major 128 B
        int o = wave * 1024 + lane * 16;
        int src = o ^ (((o >> 7) & 7) << 4);  // inverse chunk swizzle (row = o>>7)
        __builtin_amdgcn_global_load_lds(GLOBAL_AS(gB + src),
                                         LDS_AS(smem + slot * BTILE + wave * 1024),
                                         16, 0, 0);
    };

    stage(g0, 0);
    if (nt > 1) stage(g0 + 1, 1);

    int curI = -1;
    long afr[8];  // A fragments: rows I*128 + wavei*32 + ln31, all 8 k-chunks
    float la = 0.0f, lb = 0.0f;

    for (int t = 0; t < nt; ++t) {
        int I, J;
        decode(g0 + t, I, J);

        if (t + 1 < nt) asm volatile("s_waitcnt vmcnt(1)" ::: "memory");
        else            asm volatile("s_waitcnt vmcnt(0)" ::: "memory");
        __builtin_amdgcn_s_barrier();
        __builtin_amdgcn_sched_barrier(0);

        // A refresh on I-change (block-uniform branch; ~32-line gather, rare)
        if (I != curI) {
            curI = I;
            const char* gA = pb + (size_t)I * 16384 + (wavei * 32 + ln31) * 128 + h * 8;
#pragma unroll
            for (int ks = 0; ks < 8; ++ks) afr[ks] = *(const long*)(gA + ks * 16);
        }
        // j-side scalars (coalesced 32-lane load, L1/L2-hot)
        const int j = J * 64 + wavej * 32 + ln31;
        const float qj = qarr[j];
        const float wj = warr[j];

        if (t + 2 < nt) stage(g0 + t + 2, (t + 2) % 3);  // issue AFTER the barrier

        const char* lB = smem + (size_t)(t % 3) * BTILE;
        f32x16 acc = {};
#pragma unroll
        for (int ks = 0; ks < 8; ++ks) {
            int co = ((ks ^ (ln31 & 7)) << 4) + h * 8;
            long bv = *(const long*)(lB + (wavej * 32 + ln31) * 128 + co);
            acc = __builtin_amdgcn_mfma_f32_32x32x16_fp8_fp8(afr[ks], bv, acc, 0, 0, 0);
        }

        // Epilogue. C/D 32x32: col = ln31, row = (reg&3) + 8*(reg>>2) + 4*h.
        // i-row for (g,r2) = I*128 + wavei*32 + 8g + 4h + r2; q/w via broadcast f32x4.
        const bool dtype = ((J >> 1) == I);
#pragma unroll
        for (int gg = 0; gg < 4; ++gg) {
            int rbase = I * 128 + wavei * 32 + 8 * gg + 4 * h;
            f32x4v q4 = *(const f32x4v*)(qarr + rbase);
            f32x4v w4 = *(const f32x4v*)(warr + rbase);
#pragma unroll
            for (int r2 = 0; r2 < 4; ++r2) {
                float sq = fmaf(-2.0f, acc[gg * 4 + r2], q4[r2] + qj);
                if (dtype) {
                    float d = __builtin_amdgcn_sqrtf(fmaxf(sq, 0.0f));  // i==j -> ~0
                    la += fmaxf(d + w4[r2], 0.0f);
                } else {
                    float d = __builtin_amdgcn_sqrtf(sq);  // off-diag: sq >= ~0.9
                    la += fmaxf(d + w4[r2], 0.0f);   // term (i,j)
                    lb += fmaxf(d + wj, 0.0f);       // term (j,i)
                }
            }
        }
    }

    // block reduction + one atomic per block
    float local = la + lb;
#pragma unroll
    for (int m = 1; m < 64; m <<= 1) local += __shfl_xor(local, m);
    __syncthreads();
    float* sred = (float*)smem;
    if (lane == 0) sred[wave] = local;
    __syncthreads();
    if (tid == 0) {
        float t0 = (sred[0] + sred[1]) + (sred[2] + sred[3]);
        float t1 = (sred[4] + sred[5]) + (sred[6] + sred[7]);
        atomicAdd(out, (t0 + t1) * INV_DENOM);
    }
}

extern "C" void kernel_launch(void* const* d_in, const int* in_sizes, int n_in,
                              void* d_out, int out_size, void* d_ws, size_t ws_size,
                              hipStream_t stream) {
    const float* p = (const float*)d_in[0];  // [8192,128] f32
    const float* n = (const float*)d_in[1];  // [64,128] f32
    float* out = (float*)d_out;
    char* ws = (char*)d_ws;

    char*  pb    = ws;                                       // 1 MB (8192 x 128 B fp8)
    float* qarr  = (float*)(ws + (1u << 20));                // 32 KB
    float* warr  = (float*)(ws + (1u << 20) + (32u << 10));  // 32 KB

    hipLaunchKernelGGL(rows_kernel, dim3(LP / 16), dim3(64), 0, stream, p, n, pb,
                       qarr, warr, out);
    hipLaunchKernelGGL(pair_kernel, dim3(NBLK), dim3(512), 0, stream, pb, qarr, warr, out);
}

// Round 11
// 37.650 us; speedup vs baseline: 1.0424x; 1.0424x over previous
//
#include <hip/hip_runtime.h>
#include <hip/hip_bf16.h>

typedef float f32x16 __attribute__((ext_vector_type(16)));
typedef float f32x4v __attribute__((ext_vector_type(4)));

#define LP 8192
#define D 128
#define TWOEPS 2e-6f
#define CEPS 1.28e-10f   /* 128 * EPS^2 */
#define MARGIN 0.2f
#define NT32 32896       /* 256*257/2 triangular 32x32 tiles */
#define INV_DENOM 1.4903545e-8f  /* 1 / (8192*8191) */
#define CH 131072        /* K-panel chunk stride: 8192 rows x 16 B */

// ---------------- Phase A: normalize p rows -> fp8 K-panels, q8[], w[] -------------
// pbT layout: [kchunk 0..7][row 0..8191][16 B]  (chunk c = fp8 elements 16c..16c+15)
// -> pair-kernel fragment loads are 64x8B contiguous (4 cache lines/instr).
__global__ __launch_bounds__(64) void rows_kernel(const float* __restrict__ p,
                                                  const float* __restrict__ n,
                                                  char* __restrict__ pbT,
                                                  float* __restrict__ qarr,
                                                  float* __restrict__ warr,
                                                  float* __restrict__ out) {
    const int lane = threadIdx.x;
    if (blockIdx.x == 0 && lane == 0) out[0] = 0.0f;
    const int sub = lane & 3;    // quarter of the row (32 floats)
    const int r = lane >> 2;     // 0..15
    const int row = blockIdx.x * 16 + r;

    const float4* px = (const float4*)(p + (size_t)row * D + sub * 32);
    const float4* nx = (const float4*)(n + sub * 32);  // n row 0 (t=0)
    float4 x[8], y[8];
#pragma unroll
    for (int k = 0; k < 8; ++k) { x[k] = px[k]; y[k] = nx[k]; }

    float ssp = 0.0f, ssn = 0.0f;
#pragma unroll
    for (int k = 0; k < 8; ++k) {
        ssp += fmaf(x[k].x, x[k].x, fmaf(x[k].y, x[k].y,
               fmaf(x[k].z, x[k].z, x[k].w * x[k].w)));
        ssn += fmaf(y[k].x, y[k].x, fmaf(y[k].y, y[k].y,
               fmaf(y[k].z, y[k].z, y[k].w * y[k].w)));
    }
    ssp += __shfl_xor(ssp, 1); ssp += __shfl_xor(ssp, 2);
    ssn += __shfl_xor(ssn, 1); ssn += __shfl_xor(ssn, 2);

    const float invp = 1.0f / fmaxf(sqrtf(ssp), 1e-12f);
    const float invn = 1.0f / fmaxf(sqrtf(ssn), 1e-12f);

    float s = 0.0f, q = 0.0f, dn = 0.0f, sn = 0.0f, qn = 0.0f, q8 = 0.0f;
    int pk8[8];
#pragma unroll
    for (int k = 0; k < 8; ++k) {
        float a0 = x[k].x * invp, a1 = x[k].y * invp,
              a2 = x[k].z * invp, a3 = x[k].w * invp;
        float h0 = y[k].x * invn, h1 = y[k].y * invn,
              h2 = y[k].z * invn, h3 = y[k].w * invn;
        s  += (a0 + a1) + (a2 + a3);
        q  += fmaf(a0, a0, fmaf(a1, a1, fmaf(a2, a2, a3 * a3)));
        dn += fmaf(a0, h0, fmaf(a1, h1, fmaf(a2, h2, a3 * h3)));
        sn += (h0 + h1) + (h2 + h3);
        qn += fmaf(h0, h0, fmaf(h1, h1, fmaf(h2, h2, h3 * h3)));
        int wlo = __builtin_amdgcn_cvt_pk_fp8_f32(a0, a1, 0, false);
        int wfl = __builtin_amdgcn_cvt_pk_fp8_f32(a2, a3, wlo, true);
        pk8[k] = wfl;
        float b0 = __builtin_amdgcn_cvt_f32_fp8(wfl, 0);
        float b1 = __builtin_amdgcn_cvt_f32_fp8(wfl, 1);
        float b2 = __builtin_amdgcn_cvt_f32_fp8(wfl, 2);
        float b3 = __builtin_amdgcn_cvt_f32_fp8(wfl, 3);
        q8 += fmaf(b0, b0, fmaf(b1, b1, fmaf(b2, b2, b3 * b3)));
    }
    // K-panel stores: elements 32*sub..+31 = chunks 2sub, 2sub+1
    char* d0 = pbT + (size_t)(2 * sub) * CH + (size_t)row * 16;
    char* d1 = pbT + (size_t)(2 * sub + 1) * CH + (size_t)row * 16;
    *(int4*)d0 = make_int4(pk8[0], pk8[1], pk8[2], pk8[3]);
    *(int4*)d1 = make_int4(pk8[4], pk8[5], pk8[6], pk8[7]);

#pragma unroll
    for (int m = 1; m < 4; m <<= 1) {
        s += __shfl_xor(s, m);
        q += __shfl_xor(q, m);
        dn += __shfl_xor(dn, m);
        sn += __shfl_xor(sn, m);
        qn += __shfl_xor(qn, m);
        q8 += __shfl_xor(q8, m);
    }
    if (sub == 0) {
        float sq = q + qn - 2.0f * dn + TWOEPS * (s - sn) + CEPS;
        float dpn = sqrtf(fmaxf(sq, 0.0f));
        qarr[row] = q8;
        warr[row] = MARGIN - dpn;
    }
}

// ---------------- Phase B: barrier-free per-wave 32x32-tile pair kernel ------------
// Wave wid owns ~4 consecutive triangular tiles g (I >= J over 256 row-groups).
// A-frags in regs (reload on I-change), B-frags double-buffered in regs (prefetch
// next tile before current MFMAs). No LDS tiles, no s_barrier, no manual waitcnt.
// I==J tile: single term per cell with clamp; I>J: both ordered terms per dot.
#define TILE_BODY(BC, BN, T)                                                        \
  {                                                                                 \
    int I, J;                                                                       \
    decode(g0 + (T), I, J);                                                         \
    const bool hasNext = ((T) + 1 < nt);                                            \
    int In = I, Jn = J;                                                             \
    if (hasNext) decode(g0 + (T) + 1, In, Jn);                                      \
    if (hasNext) {                                                                  \
      const char* gB = pbT + (size_t)(Jn * 32 + ln31) * 16 + h * 8;                 \
      _Pragma("unroll") for (int ks = 0; ks < 8; ++ks)                              \
          BN[ks] = *(const long*)(gB + (size_t)ks * CH);                            \
    }                                                                               \
    const int j = J * 32 + ln31;                                                    \
    const float qj = qarr[j];                                                       \
    const float wj = warr[j];                                                       \
    f32x16 acc = {};                                                                \
    _Pragma("unroll") for (int ks = 0; ks < 8; ++ks)                                \
        acc = __builtin_amdgcn_mfma_f32_32x32x16_fp8_fp8(a_[ks], BC[ks], acc,       \
                                                         0, 0, 0);                  \
    const bool dtype = (I == J);                                                    \
    _Pragma("unroll") for (int gg = 0; gg < 4; ++gg) {                              \
      int rbase = I * 32 + 8 * gg + 4 * h;                                          \
      f32x4v q4 = *(const f32x4v*)(qarr + rbase);                                   \
      f32x4v w4 = *(const f32x4v*)(warr + rbase);                                   \
      _Pragma("unroll") for (int r2 = 0; r2 < 4; ++r2) {                            \
        float sq = fmaf(-2.0f, acc[gg * 4 + r2], q4[r2] + qj);                      \
        if (dtype) {                                                                \
          float d = __builtin_amdgcn_sqrtf(fmaxf(sq, 0.0f));  /* i==j -> ~0 */      \
          la += fmaxf(d + w4[r2], 0.0f);                                            \
        } else {                                                                    \
          float d = __builtin_amdgcn_sqrtf(sq);  /* off-diag: sq >= ~0.9 */         \
          la += fmaxf(d + w4[r2], 0.0f);   /* term (i,j) */                         \
          lb += fmaxf(d + wj, 0.0f);       /* term (j,i) */                         \
        }                                                                           \
      }                                                                             \
    }                                                                               \
    if (hasNext && In != I) {                                                       \
      const char* gA = pbT + (size_t)(In * 32 + ln31) * 16 + h * 8;                 \
      _Pragma("unroll") for (int ks = 0; ks < 8; ++ks)                              \
          a_[ks] = *(const long*)(gA + (size_t)ks * CH);                            \
    }                                                                               \
  }

__global__ __launch_bounds__(512, 4) void pair_kernel(const char* __restrict__ pbT,
                                                      const float* __restrict__ qarr,
                                                      const float* __restrict__ warr,
                                                      float* __restrict__ out) {
    __shared__ float sred[8];
    const int tid = threadIdx.x;
    const int wave = tid >> 6, lane = tid & 63;
    const int ln31 = lane & 31;
    const int h = lane >> 5;

    const int wid = blockIdx.x * 8 + wave;              // 0..8191
    const int g0 = wid * 4 + (wid < 128 ? wid : 128);   // 8192*4 + 128 = 32896 tiles
    const int nt = 4 + (wid < 128);

    auto decode = [](int g, int& I, int& J) {
        int t = (int)((__builtin_amdgcn_sqrtf(8.0f * (float)g + 1.0f) - 1.0f) * 0.5f);
        while ((t + 1) * (t + 2) / 2 <= g) ++t;
        while (t * (t + 1) / 2 > g) --t;
        I = t;
        J = g - t * (t + 1) / 2;
    };

    long a_[8], b0_[8], b1_[8];
    {
        int I0, J0;
        decode(g0, I0, J0);
        const char* gA = pbT + (size_t)(I0 * 32 + ln31) * 16 + h * 8;
        const char* gB = pbT + (size_t)(J0 * 32 + ln31) * 16 + h * 8;
#pragma unroll
        for (int ks = 0; ks < 8; ++ks) {
            a_[ks] = *(const long*)(gA + (size_t)ks * CH);
            b0_[ks] = *(const long*)(gB + (size_t)ks * CH);
        }
    }

    float la = 0.0f, lb = 0.0f;
    int t = 0;
    for (; t + 1 < nt; t += 2) {
        TILE_BODY(b0_, b1_, t)
        TILE_BODY(b1_, b0_, t + 1)
    }
    if (t < nt) TILE_BODY(b0_, b1_, t)

    // block reduction + one atomic per block
    float local = la + lb;
#pragma unroll
    for (int m = 1; m < 64; m <<= 1) local += __shfl_xor(local, m);
    if (lane == 0) sred[wave] = local;
    __syncthreads();
    if (tid == 0) {
        float t0 = (sred[0] + sred[1]) + (sred[2] + sred[3]);
        float t1 = (sred[4] + sred[5]) + (sred[6] + sred[7]);
        atomicAdd(out, (t0 + t1) * INV_DENOM);
    }
}

extern "C" void kernel_launch(void* const* d_in, const int* in_sizes, int n_in,
                              void* d_out, int out_size, void* d_ws, size_t ws_size,
                              hipStream_t stream) {
    const float* p = (const float*)d_in[0];  // [8192,128] f32
    const float* n = (const float*)d_in[1];  // [64,128] f32
    float* out = (float*)d_out;
    char* ws = (char*)d_ws;

    char*  pbT  = ws;                                       // 1 MB K-panel fp8
    float* qarr = (float*)(ws + (1u << 20));                // 32 KB
    float* warr = (float*)(ws + (1u << 20) + (32u << 10));  // 32 KB

    hipLaunchKernelGGL(rows_kernel, dim3(LP / 16), dim3(64), 0, stream, p, n, pbT,
                       qarr, warr, out);
    hipLaunchKernelGGL(pair_kernel, dim3(1024), dim3(512), 0, stream, pbT, qarr,
                       warr, out);
}